// Round 8
// baseline (258.869 us; speedup 1.0000x reference)
//
#include <hip/hip_runtime.h>

#define NBINS 64
#define NGRAPH 64
#define HID 256
#define TILE 128
#define NPAIR 36            // ti<=tj tile pairs
#define NSUB 32             // wave-private sub-histograms (8 per wave)
#define HSTR 65             // 64 real bins + trash bin 64; sub-major stride

// triangular tile-pair lookup (p -> (ti,tj), ti<=tj)
__device__ __constant__ unsigned char ti_tab[NPAIR] = {
  0,0,0,0,0,0,0,0, 1,1,1,1,1,1,1, 2,2,2,2,2,2, 3,3,3,3,3, 4,4,4,4, 5,5,5, 6,6, 7};
__device__ __constant__ unsigned char tj_tab[NPAIR] = {
  0,1,2,3,4,5,6,7, 1,2,3,4,5,6,7, 2,3,4,5,6,7, 3,4,5,6,7, 4,5,6,7, 5,6,7, 6,7, 7};

// Branch-free inner loop; positions pre-scaled by 2.56 so bin = (int)sqrt(d2);
// d>=25 or masked diagonal pairs land in trash bin 64 (dropped at flush).
// hw points at this thread's wave-private sub-histogram (stride-65 layout:
// bank = (sub+bin)&31 -> ~2 lanes/bank, no cross-wave same-address RMW).
template <bool OFFDIAG>
__device__ __forceinline__ void pair_loop(const float4* __restrict__ plj,
                                          unsigned int* __restrict__ hw,
                                          float4 pa, float4 pb, int il0, int il1,
                                          int jbase) {
  #pragma unroll 8
  for (int jj = 0; jj < 32; ++jj) {
    int jl = jbase + jj;
    float4 pj = plj[jl];                  // wave-uniform broadcast ds_read_b128
    float dxa = pa.x - pj.x, dya = pa.y - pj.y, dza = pa.z - pj.z;
    float d2a = dxa * dxa + dya * dya + dza * dza;
    float dxb = pb.x - pj.x, dyb = pb.y - pj.y, dzb = pb.z - pj.z;
    float d2b = dxb * dxb + dyb * dyb + dzb * dzb;
    unsigned int ia = (unsigned int)(int)__builtin_amdgcn_sqrtf(d2a);
    unsigned int ib = (unsigned int)(int)__builtin_amdgcn_sqrtf(d2b);
    ia = ia > 64u ? 64u : ia;             // v_min_u32
    ib = ib > 64u ? 64u : ib;
    if (!OFFDIAG) {                       // diag blocks: route i>=j to trash
      ia = (il0 < jl) ? ia : 64u;
      ib = (il1 < jl) ? ib : 64u;
    }
    atomicAdd(&hw[ia], 1u);               // unconditional ds_add_u32
    atomicAdd(&hw[ib], 1u);
  }
}

// -------- Fused kernel: hist blocks + last-arriver-per-graph runs the MLP ----
__global__ __launch_bounds__(256) void fused_kernel(
    const float* __restrict__ pos,
    const float* __restrict__ W1, const float* __restrict__ b1,
    const float* __restrict__ W2, const float* __restrict__ b2,
    unsigned int* __restrict__ ghist,   // [NGRAPH*NBINS], zeroed by memset
    unsigned int* __restrict__ cnt,     // [NGRAPH], zeroed by memset
    float* __restrict__ out) {
  int bid = blockIdx.x;
  int g   = bid / NPAIR;
  int p   = bid - g * NPAIR;
  int ti  = ti_tab[p];
  int tj  = tj_tab[p];
  int t   = threadIdx.x;
  const float S = 2.56f;                  // NBINS / MAX_DIST

  __shared__ float4 plj[TILE];            // 2 KB j-tile (pre-scaled)
  __shared__ unsigned int h[NSUB * HSTR]; // 8320 B sub-histograms, sub-major
  __shared__ float hn[NBINS];
  __shared__ float h1[HID];
  __shared__ unsigned int arrival;

  for (int k = t; k < NSUB * HSTR; k += 256) h[k] = 0u;
  if (t < TILE) {
    const float* gp = pos + (size_t)((g << 10) + (tj << 7) + t) * 3;
    plj[t] = make_float4(gp[0] * S, gp[1] * S, gp[2] * S, 0.0f);
  }

  int il0 = (t & 63) * 2;                 // 2 i's per thread, direct from global
  int il1 = il0 + 1;
  const float* ip = pos + (size_t)((g << 10) + (ti << 7) + il0) * 3;
  float4 pa = make_float4(ip[0] * S, ip[1] * S, ip[2] * S, 0.0f);
  float4 pb = make_float4(ip[3] * S, ip[4] * S, ip[5] * S, 0.0f);
  int jbase = (t >> 6) * 32;              // j-quarter per wave (uniform)
  unsigned int* hw = h + ((t >> 6) * 8 + (t & 7)) * HSTR;  // wave-private sub
  __syncthreads();

  if (ti != tj) pair_loop<true >(plj, hw, pa, pb, il0, il1, jbase);
  else          pair_loop<false>(plj, hw, pa, pb, il0, il1, jbase);
  __syncthreads();

  if (t < NBINS) {                        // flush (trash bin 64 dropped)
    unsigned int s = 0u;
    #pragma unroll
    for (int k = 0; k < NSUB; ++k) s += h[k * HSTR + t];
    atomicAdd(&ghist[g * NBINS + t], s);  // device-scope global atomic
  }
  __threadfence();                        // release our ghist adds
  __syncthreads();
  if (t == 0) arrival = atomicAdd(&cnt[g], 1u);
  __syncthreads();
  if (arrival != NPAIR - 1) return;       // uniform per block
  __threadfence();                        // acquire side before reading ghist

  // ---- winner block: normalize + 2-layer MLP for graph g ----
  if (t < NBINS) {                        // wave 0
    unsigned int s = __hip_atomic_load(&ghist[g * NBINS + t],
                                       __ATOMIC_RELAXED, __HIP_MEMORY_SCOPE_AGENT);
    float hv = (float)s;                  // exact: < 2^23
    float tot = hv;
    #pragma unroll
    for (int m = 1; m < 64; m <<= 1) tot += __shfl_xor(tot, m, 64);
    hn[t] = hv / (tot + 1e-8f);
  }
  __syncthreads();

  // layer 1: h1 = silu(hn @ W1^T + b1), thread t -> channel t
  {
    float acc = b1[t];
    const float4* w = (const float4*)(W1 + (size_t)t * NBINS);
    #pragma unroll
    for (int k = 0; k < NBINS / 4; ++k) {
      float4 wv = w[k];
      acc += hn[4 * k] * wv.x + hn[4 * k + 1] * wv.y +
             hn[4 * k + 2] * wv.z + hn[4 * k + 3] * wv.w;
    }
    float sig = 1.0f / (1.0f + expf(-acc));
    h1[t] = acc * sig;
  }
  __syncthreads();

  // layer 2: thread t -> output t (4 partial accumulators, then combine)
  {
    float ax = 0.f, ay = 0.f, az = 0.f, aw = 0.f;
    const float4* w = (const float4*)(W2 + (size_t)t * HID);
    #pragma unroll 8
    for (int k = 0; k < HID / 4; ++k) {
      float4 wv = w[k];
      ax += h1[4 * k] * wv.x;  ay += h1[4 * k + 1] * wv.y;
      az += h1[4 * k + 2] * wv.z;  aw += h1[4 * k + 3] * wv.w;
    }
    out[(size_t)g * HID + t] = b2[t] + ((ax + ay) + (az + aw));
  }
}

extern "C" void kernel_launch(void* const* d_in, const int* in_sizes, int n_in,
                              void* d_out, int out_size, void* d_ws, size_t ws_size,
                              hipStream_t stream) {
  const float* pos = (const float*)d_in[0];
  const float* W1  = (const float*)d_in[1];
  const float* b1  = (const float*)d_in[2];
  const float* W2  = (const float*)d_in[3];
  const float* b2  = (const float*)d_in[4];
  // d_in[5] = batch ids: unused (contiguous equal-size segments by construction)

  unsigned int* ghist = (unsigned int*)d_ws;            // 16 KB
  unsigned int* cnt   = ghist + NGRAPH * NBINS;         // 256 B
  hipMemsetAsync(d_ws, 0, (NGRAPH * NBINS + NGRAPH) * sizeof(unsigned int), stream);

  hipLaunchKernelGGL(fused_kernel, dim3(NGRAPH * NPAIR), dim3(256), 0, stream,
                     pos, W1, b1, W2, b2, ghist, cnt, (float*)d_out);
}

// Round 9
// 125.593 us; speedup vs baseline: 2.0612x; 2.0612x over previous
//
#include <hip/hip_runtime.h>

#define NBINS 64
#define NGRAPH 64
#define HID 256
#define TILE 128
#define NPAIR 36            // ti<=tj tile pairs
#define NSUB 32             // wave-private sub-histograms (8 per wave)
#define HSTR 65             // 64 real bins + trash bin 64; sub-major stride

// triangular tile-pair lookup (p -> (ti,tj), ti<=tj)
__device__ __constant__ unsigned char ti_tab[NPAIR] = {
  0,0,0,0,0,0,0,0, 1,1,1,1,1,1,1, 2,2,2,2,2,2, 3,3,3,3,3, 4,4,4,4, 5,5,5, 6,6, 7};
__device__ __constant__ unsigned char tj_tab[NPAIR] = {
  0,1,2,3,4,5,6,7, 1,2,3,4,5,6,7, 2,3,4,5,6,7, 3,4,5,6,7, 4,5,6,7, 5,6,7, 6,7, 7};

// Branch-free inner loop; positions pre-scaled by 2.56 so bin = (int)sqrt(d2);
// d>=25 or masked diagonal pairs land in trash bin 64 (dropped at flush).
template <bool OFFDIAG>
__device__ __forceinline__ void pair_loop(const float4* __restrict__ plj,
                                          unsigned int* __restrict__ hw,
                                          float4 pa, float4 pb, int il0, int il1,
                                          int jbase) {
  #pragma unroll 8
  for (int jj = 0; jj < 32; ++jj) {
    int jl = jbase + jj;
    float4 pj = plj[jl];                  // wave-uniform broadcast ds_read_b128
    float dxa = pa.x - pj.x, dya = pa.y - pj.y, dza = pa.z - pj.z;
    float d2a = dxa * dxa + dya * dya + dza * dza;
    float dxb = pb.x - pj.x, dyb = pb.y - pj.y, dzb = pb.z - pj.z;
    float d2b = dxb * dxb + dyb * dyb + dzb * dzb;
    unsigned int ia = (unsigned int)(int)__builtin_amdgcn_sqrtf(d2a);
    unsigned int ib = (unsigned int)(int)__builtin_amdgcn_sqrtf(d2b);
    ia = ia > 64u ? 64u : ia;             // v_min_u32
    ib = ib > 64u ? 64u : ib;
    if (!OFFDIAG) {                       // diag blocks: route i>=j to trash
      ia = (il0 < jl) ? ia : 64u;
      ib = (il1 < jl) ? ib : 64u;
    }
    atomicAdd(&hw[ia], 1u);               // unconditional ds_add_u32
    atomicAdd(&hw[ib], 1u);
  }
}

// -------- Fused kernel: hist blocks + last-arriver-per-graph runs the MLP ----
// Cross-block protocol is PURE ATOMIC RMW (MALL-coherent on gfx950) — no
// __threadfence (agent fences emit per-XCD L2 writeback/invalidate = R8's
// 226us stall). Ordering: returning ghist fetch_add completes (vmcnt) before
// wave 0 bumps cnt; winner re-reads ghist via fetch_add(+0) RMWs.
__global__ __launch_bounds__(256) void fused_kernel(
    const float* __restrict__ pos,
    const float* __restrict__ W1, const float* __restrict__ b1,
    const float* __restrict__ W2, const float* __restrict__ b2,
    unsigned int* __restrict__ ghist,   // [NGRAPH*NBINS], zeroed by memset
    unsigned int* __restrict__ cnt,     // [NGRAPH], zeroed by memset
    float* __restrict__ out) {
  int bid = blockIdx.x;
  int g   = bid / NPAIR;
  int p   = bid - g * NPAIR;
  int ti  = ti_tab[p];
  int tj  = tj_tab[p];
  int t   = threadIdx.x;
  const float S = 2.56f;                  // NBINS / MAX_DIST

  __shared__ float4 plj[TILE];            // 2 KB j-tile (pre-scaled)
  __shared__ unsigned int h[NSUB * HSTR]; // 8320 B sub-histograms, sub-major
  __shared__ float hn[NBINS];
  __shared__ float h1[HID];
  __shared__ unsigned int arrival;

  for (int k = t; k < NSUB * HSTR; k += 256) h[k] = 0u;
  if (t < TILE) {
    const float* gp = pos + (size_t)((g << 10) + (tj << 7) + t) * 3;
    plj[t] = make_float4(gp[0] * S, gp[1] * S, gp[2] * S, 0.0f);
  }

  int il0 = (t & 63) * 2;                 // 2 i's per thread, direct from global
  int il1 = il0 + 1;
  const float* ip = pos + (size_t)((g << 10) + (ti << 7) + il0) * 3;
  float4 pa = make_float4(ip[0] * S, ip[1] * S, ip[2] * S, 0.0f);
  float4 pb = make_float4(ip[3] * S, ip[4] * S, ip[5] * S, 0.0f);
  int jbase = (t >> 6) * 32;              // j-quarter per wave (uniform)
  unsigned int* hw = h + ((t >> 6) * 8 + (t & 7)) * HSTR;  // wave-private sub
  __syncthreads();

  if (ti != tj) pair_loop<true >(plj, hw, pa, pb, il0, il1, jbase);
  else          pair_loop<false>(plj, hw, pa, pb, il0, il1, jbase);
  __syncthreads();

  if (t < NBINS) {                        // flush (trash bin 64 dropped)
    unsigned int s = 0u;
    #pragma unroll
    for (int k = 0; k < NSUB; ++k) s += h[k * HSTR + t];
    // returning form: result live -> sc0; vmcnt retire == RMW done at MALL
    unsigned int old = __hip_atomic_fetch_add(&ghist[g * NBINS + t], s,
                          __ATOMIC_RELAXED, __HIP_MEMORY_SCOPE_AGENT);
    asm volatile("" :: "v"(old));
  }
  __syncthreads();                        // drains vmcnt for wave 0 as well
  if (t == 0) {
    asm volatile("s_waitcnt vmcnt(0)" ::: "memory");  // belt-and-suspenders
    arrival = __hip_atomic_fetch_add(&cnt[g], 1u,
                 __ATOMIC_RELAXED, __HIP_MEMORY_SCOPE_AGENT);
  }
  __syncthreads();
  if (arrival != NPAIR - 1) return;       // uniform per block

  // ---- winner block: normalize + 2-layer MLP for graph g ----
  if (t < NBINS) {                        // wave 0; RMW read = MALL-coherent
    unsigned int s = __hip_atomic_fetch_add(&ghist[g * NBINS + t], 0u,
                        __ATOMIC_RELAXED, __HIP_MEMORY_SCOPE_AGENT);
    float hv = (float)s;                  // exact: < 2^23
    float tot = hv;
    #pragma unroll
    for (int m = 1; m < 64; m <<= 1) tot += __shfl_xor(tot, m, 64);
    hn[t] = hv / (tot + 1e-8f);
  }
  __syncthreads();

  // layer 1: h1 = silu(hn @ W1^T + b1), thread t -> channel t
  {
    float acc = b1[t];
    const float4* w = (const float4*)(W1 + (size_t)t * NBINS);
    #pragma unroll
    for (int k = 0; k < NBINS / 4; ++k) {
      float4 wv = w[k];
      acc += hn[4 * k] * wv.x + hn[4 * k + 1] * wv.y +
             hn[4 * k + 2] * wv.z + hn[4 * k + 3] * wv.w;
    }
    float sig = 1.0f / (1.0f + expf(-acc));
    h1[t] = acc * sig;
  }
  __syncthreads();

  // layer 2: thread t -> output t (4 partial accumulators, then combine)
  {
    float ax = 0.f, ay = 0.f, az = 0.f, aw = 0.f;
    const float4* w = (const float4*)(W2 + (size_t)t * HID);
    #pragma unroll 8
    for (int k = 0; k < HID / 4; ++k) {
      float4 wv = w[k];
      ax += h1[4 * k] * wv.x;  ay += h1[4 * k + 1] * wv.y;
      az += h1[4 * k + 2] * wv.z;  aw += h1[4 * k + 3] * wv.w;
    }
    out[(size_t)g * HID + t] = b2[t] + ((ax + ay) + (az + aw));
  }
}

extern "C" void kernel_launch(void* const* d_in, const int* in_sizes, int n_in,
                              void* d_out, int out_size, void* d_ws, size_t ws_size,
                              hipStream_t stream) {
  const float* pos = (const float*)d_in[0];
  const float* W1  = (const float*)d_in[1];
  const float* b1  = (const float*)d_in[2];
  const float* W2  = (const float*)d_in[3];
  const float* b2  = (const float*)d_in[4];
  // d_in[5] = batch ids: unused (contiguous equal-size segments by construction)

  unsigned int* ghist = (unsigned int*)d_ws;            // 16 KB
  unsigned int* cnt   = ghist + NGRAPH * NBINS;         // 256 B
  hipMemsetAsync(d_ws, 0, (NGRAPH * NBINS + NGRAPH) * sizeof(unsigned int), stream);

  hipLaunchKernelGGL(fused_kernel, dim3(NGRAPH * NPAIR), dim3(256), 0, stream,
                     pos, W1, b1, W2, b2, ghist, cnt, (float*)d_out);
}

// Round 10
// 86.323 us; speedup vs baseline: 2.9988x; 1.4549x over previous
//
#include <hip/hip_runtime.h>

#define NBINS 64
#define NGRAPH 64
#define HID 256
#define TILE 128
#define NPAIR 36            // ti<=tj tile pairs
#define BPG NPAIR           // hist blocks per graph
#define WSUB 16             // sub-histograms per wave (4 lanes share one)
#define NSUB 64             // total subs = 4 waves * WSUB
#define HSTR 65             // 64 real bins + trash bin 64; sub-major stride

// triangular tile-pair lookup (p -> (ti,tj), ti<=tj)
__device__ __constant__ unsigned char ti_tab[NPAIR] = {
  0,0,0,0,0,0,0,0, 1,1,1,1,1,1,1, 2,2,2,2,2,2, 3,3,3,3,3, 4,4,4,4, 5,5,5, 6,6, 7};
__device__ __constant__ unsigned char tj_tab[NPAIR] = {
  0,1,2,3,4,5,6,7, 1,2,3,4,5,6,7, 2,3,4,5,6,7, 3,4,5,6,7, 4,5,6,7, 5,6,7, 6,7, 7};

// Branch-free inner loop; positions pre-scaled by 2.56 so bin = (int)sqrt(d2);
// d>=25 or masked diagonal pairs land in trash bin 64 (dropped at flush).
// hw: this thread's sub-histogram (4 lanes share -> worst case 4-way
// same-address RMW ~1.58x, vs 8-way ~2.94x before). Stride 65 spreads a
// sub's bins across all banks.
template <bool OFFDIAG>
__device__ __forceinline__ void pair_loop(const float4* __restrict__ plj,
                                          unsigned int* __restrict__ hw,
                                          float4 pa, float4 pb, int il0, int il1,
                                          int jbase) {
  #pragma unroll 8
  for (int jj = 0; jj < 32; ++jj) {
    int jl = jbase + jj;
    float4 pj = plj[jl];                  // wave-uniform broadcast ds_read_b128
    float dxa = pa.x - pj.x, dya = pa.y - pj.y, dza = pa.z - pj.z;
    float d2a = dxa * dxa + dya * dya + dza * dza;
    float dxb = pb.x - pj.x, dyb = pb.y - pj.y, dzb = pb.z - pj.z;
    float d2b = dxb * dxb + dyb * dyb + dzb * dzb;
    unsigned int ia = (unsigned int)(int)__builtin_amdgcn_sqrtf(d2a);
    unsigned int ib = (unsigned int)(int)__builtin_amdgcn_sqrtf(d2b);
    ia = ia > 64u ? 64u : ia;             // v_min_u32
    ib = ib > 64u ? 64u : ib;
    if (!OFFDIAG) {                       // diag blocks: route i>=j to trash
      ia = (il0 < jl) ? ia : 64u;
      ib = (il1 < jl) ? ib : 64u;
    }
    atomicAdd(&hw[ia], 1u);               // unconditional ds_add_u32
    atomicAdd(&hw[ib], 1u);
  }
}

// -------- Kernel 1: triangular tiled pairwise-distance histogram --------
// Block = (graph, tile-pair). Each unordered i<j pair counted exactly once.
__global__ __launch_bounds__(256) void hist_kernel(const float* __restrict__ pos,
                                                   unsigned int* __restrict__ partial) {
  int bid = blockIdx.x;
  int g   = bid / NPAIR;
  int p   = bid - g * NPAIR;
  int ti  = ti_tab[p];
  int tj  = tj_tab[p];
  int t   = threadIdx.x;
  const float S = 2.56f;                  // NBINS / MAX_DIST

  __shared__ float4 plj[TILE];                 // 2 KB j-tile (pre-scaled)
  __shared__ unsigned int h[NSUB * HSTR];      // 16.6 KB sub-histograms

  #pragma unroll
  for (int k = t; k < NSUB * HSTR; k += 256) h[k] = 0u;
  if (t < TILE) {
    const float* gp = pos + (size_t)((g << 10) + (tj << 7) + t) * 3;
    plj[t] = make_float4(gp[0] * S, gp[1] * S, gp[2] * S, 0.0f);
  }

  // thread t: i-pair (2*(t&63), 2*(t&63)+1) read directly from global
  int il0 = (t & 63) * 2;
  int il1 = il0 + 1;
  const float* ip = pos + (size_t)((g << 10) + (ti << 7) + il0) * 3;
  float4 pa = make_float4(ip[0] * S, ip[1] * S, ip[2] * S, 0.0f);
  float4 pb = make_float4(ip[3] * S, ip[4] * S, ip[5] * S, 0.0f);
  int jbase = (t >> 6) * 32;              // j-quarter per wave (uniform)
  unsigned int* hw = h + ((t >> 6) * WSUB + (t & (WSUB - 1))) * HSTR;
  __syncthreads();

  if (ti != tj) pair_loop<true >(plj, hw, pa, pb, il0, il1, jbase);
  else          pair_loop<false>(plj, hw, pa, pb, il0, il1, jbase);
  __syncthreads();

  if (t < NBINS) {                        // flush (trash bin 64 dropped)
    unsigned int s = 0u;
    #pragma unroll
    for (int k = 0; k < NSUB; ++k) s += h[k * HSTR + t];
    partial[(size_t)bid * NBINS + t] = s;
  }
}

// -------- Kernel 2: partial-sum + normalize + 2-layer MLP --------
// Block = (graph, output-quarter). layer1 redundant per quarter (cheap);
// layer2 k-sliced across the 4 waves.
__global__ __launch_bounds__(256) void mlp_kernel(const unsigned int* __restrict__ partial,
                                                  const float* __restrict__ W1,
                                                  const float* __restrict__ b1,
                                                  const float* __restrict__ W2,
                                                  const float* __restrict__ b2,
                                                  float* __restrict__ out) {
  int g = blockIdx.x >> 2;
  int q = blockIdx.x & 3;
  int t = threadIdx.x;
  __shared__ float hn[NBINS];
  __shared__ float h1[HID];
  __shared__ float p2[4][NBINS];

  if (t < NBINS) { // wave 0: assemble histogram, normalize
    unsigned int s = 0u;
    const unsigned int* pp = partial + (size_t)g * BPG * NBINS + t;
    #pragma unroll
    for (int p = 0; p < BPG; ++p) s += pp[p * NBINS];
    float hv = (float)s;                 // exact: < 2^23
    float tot = hv;
    #pragma unroll
    for (int m = 1; m < 64; m <<= 1) tot += __shfl_xor(tot, m, 64);
    hn[t] = hv / (tot + 1e-8f);
  }
  __syncthreads();

  // layer 1: h1 = silu(hn @ W1^T + b1), thread t -> channel t (float4 row)
  {
    float acc = b1[t];
    const float4* w = (const float4*)(W1 + (size_t)t * NBINS);
    #pragma unroll
    for (int k = 0; k < NBINS / 4; ++k) {
      float4 wv = w[k];
      acc += hn[4 * k] * wv.x + hn[4 * k + 1] * wv.y +
             hn[4 * k + 2] * wv.z + hn[4 * k + 3] * wv.w;
    }
    float sig = 1.0f / (1.0f + expf(-acc));
    h1[t] = acc * sig;
  }
  __syncthreads();

  // layer 2: 64 outputs (quarter q), k sliced over 4 waves
  {
    int o  = (q << 6) + (t & 63);
    int ks = (t >> 6) << 6;              // 64-wide k-slice per wave
    float acc = 0.0f;
    const float4* w = (const float4*)(W2 + (size_t)o * HID + ks);
    #pragma unroll
    for (int k = 0; k < 16; ++k) {
      float4 wv = w[k];
      acc += h1[ks + 4 * k] * wv.x + h1[ks + 4 * k + 1] * wv.y +
             h1[ks + 4 * k + 2] * wv.z + h1[ks + 4 * k + 3] * wv.w;
    }
    p2[t >> 6][t & 63] = acc;
  }
  __syncthreads();

  if (t < 64) {
    int o = (q << 6) + t;
    out[(size_t)g * HID + o] = b2[o] + p2[0][t] + p2[1][t] + p2[2][t] + p2[3][t];
  }
}

extern "C" void kernel_launch(void* const* d_in, const int* in_sizes, int n_in,
                              void* d_out, int out_size, void* d_ws, size_t ws_size,
                              hipStream_t stream) {
  const float* pos = (const float*)d_in[0];
  const float* W1  = (const float*)d_in[1];
  const float* b1  = (const float*)d_in[2];
  const float* W2  = (const float*)d_in[3];
  const float* b2  = (const float*)d_in[4];
  // d_in[5] = batch ids: unused (contiguous equal-size segments by construction)

  unsigned int* partial = (unsigned int*)d_ws; // 2304 * 64 * 4 = 576 KB scratch

  hipLaunchKernelGGL(hist_kernel, dim3(NGRAPH * BPG), dim3(256), 0, stream, pos, partial);
  hipLaunchKernelGGL(mlp_kernel, dim3(NGRAPH * 4), dim3(256), 0, stream,
                     partial, W1, b1, W2, b2, (float*)d_out);
}